// Round 5
// baseline (9544.070 us; speedup 1.0000x reference)
//
#include <hip/hip_runtime.h>
#include <stdint.h>

#define NN 4096
#define VD 8192
#define NE 65536
#define NSTEPS 100
#define CSR_CAP 98304  // 65536 + worst-case per-node pad (<= 7*4096) rounded up

#define NWG 256        // persistent grid: 1 WG per CU
#define TPB 1024
#define GWG 8          // GNN workgroups (bids 0,32,64,...,224 -> same XCD under round-robin)
#define MVW (NWG - GWG)
#define SSTR 160       // barrier slot ints per step (EX:0..6, UREADY:8, VDONE: 32+j*16)
#define BARN (NSTEPS * SSTR)

// ---------- helpers ----------
__device__ __forceinline__ uint32_t f2bf(float f) {
    uint32_t x = __float_as_uint(f);
    return (x + 0x7FFFu + ((x >> 16) & 1u)) >> 16;
}
__device__ __forceinline__ float bfl(uint32_t w) { return __uint_as_float(w << 16); }
__device__ __forceinline__ float bfh(uint32_t w) { return __uint_as_float(w & 0xFFFF0000u); }

__device__ __forceinline__ void arrive(int* flag) {
    __hip_atomic_fetch_add(flag, 1, __ATOMIC_RELEASE, __HIP_MEMORY_SCOPE_AGENT);
}
template <int SLP>
__device__ __forceinline__ void spin_ge(int* flag, int target) {
    int it = 0;
    while (__hip_atomic_load(flag, __ATOMIC_RELAXED, __HIP_MEMORY_SCOPE_AGENT) < target) {
        __builtin_amdgcn_s_sleep(SLP);
        if (++it > (1 << 22)) break;  // safety bail: wrong answer beats hang
    }
}

// ---------- setup kernels ----------
__global__ void k_zero(int* deg, int* fill, float* v0, uint32_t* csrw, int* bar) {
    int t = blockIdx.x * 256 + threadIdx.x;           // grid covers 49152
    if (t < 4096) { deg[t] = 0; fill[t] = 0; }
    if (t < 8192) v0[t] = 0.f;                        // vring slot 0
    if (t < BARN) bar[t] = 0;                         // barrier slots (monotonic per slot)
    if (t < CSR_CAP / 2) csrw[t] = 0x10001000u;       // sentinel src = 4096
}

__global__ void k_deg(const int* ei, int* deg) {
    int e = blockIdx.x * 256 + threadIdx.x;
    if (e < NE) atomicAdd(&deg[ei[NE + e]], 1);
}

__global__ __launch_bounds__(1024) void k_scan(const int* deg, int* pad_ptr, float* dinv) {
    __shared__ int sh[1024];
    int t = threadIdx.x;
    int d[4], pl[4], tsum = 0;
    for (int j = 0; j < 4; ++j) {
        d[j] = deg[t * 4 + j];
        pl[j] = (d[j] + 7) & ~7;
        tsum += pl[j];
    }
    sh[t] = tsum;
    __syncthreads();
    for (int off = 1; off < 1024; off <<= 1) {
        int v = sh[t];
        if (t >= off) v += sh[t - off];
        __syncthreads();
        sh[t] = v;
        __syncthreads();
    }
    int base = sh[t] - tsum;  // exclusive prefix
    for (int j = 0; j < 4; ++j) {
        pad_ptr[t * 4 + j] = base;
        base += pl[j];
        dinv[t * 4 + j] = rsqrtf((float)(d[j] + 1));  // +1 self loop, always > 0
    }
    if (t == 0) dinv[4096] = 0.f;  // sentinel
}

__global__ void k_fill(const int* ei, const int* pad_ptr, int* fill, uint16_t* csr) {
    int e = blockIdx.x * 256 + threadIdx.x;
    if (e < NE) {
        int s = ei[e];
        int d = ei[NE + e];
        int pos = atomicAdd(&fill[d], 1);
        csr[pad_ptr[d] + pos] = (uint16_t)s;
    }
}

__global__ void k_r(const int* deg, const int* pad_ptr, const uint16_t* csr,
                    const float* dinv, float* rr) {
    int n = blockIdx.x * 256 + threadIdx.x;
    if (n >= NN) return;
    float dv = dinv[n];
    int base = pad_ptr[n];
    int nch = (deg[n] + 7) >> 3;
    float sum = 0.f;
    for (int c = 0; c < nch; ++c)
        for (int k = 0; k < 8; ++k) sum += dinv[csr[base + c * 8 + k]];  // sentinel adds 0
    rr[n] = dv * sum + dv * dv;
}

__global__ void k_m(const float* A, const float* B, const float* bw, float* m) {
    int t = blockIdx.x * 256 + threadIdx.x;  // 65536
    if (t >= VD * 8) return;
    int i = t >> 3, k = t & 7;
    m[t] = A[(size_t)i * 8200 + 8192 + k] + B[(size_t)i * 8200 + 8192 + k] + bw[i * 8 + k];
}

__global__ __launch_bounds__(256) void k_az(const float* A, const float* z, float* az) {
    int wave = threadIdx.x >> 6, lane = threadIdx.x & 63;
    int r = blockIdx.x * 4 + wave;
    const float* row = A + (size_t)r * 8200;
    float acc = 0.f;
    for (int j = 0; j < 32; ++j) {
        int c = j * 256 + lane * 4;
        float4 a = *(const float4*)(row + c);
        float4 zz = *(const float4*)(z + c);
        acc += a.x * zz.x + a.y * zz.y + a.z * zz.z + a.w * zz.w;
    }
    for (int o = 32; o; o >>= 1) acc += __shfl_down(acc, o);
    if (lane == 0) az[r] = acc;
}

// Permuted B16 layout: row r, uint4 index p = jj*64 + l holds bf16 of cols
// {jj*512+4l .. +3} (words x,y) and {jj*512+256+4l .. +3} (words z,w).
// This makes the mv-phase su reads two stride-4 float4s -> conflict-free LDS.
__global__ __launch_bounds__(256) void k_bconv(const float* B, uint16_t* B16) {
    int t = blockIdx.x * 256 + threadIdx.x;  // VD*1024 threads, one uint4 each
    int i = t >> 10;
    int p = t & 1023;
    int jj = p >> 6, l = p & 63;
    const float* pr = B + (size_t)i * 8200 + jj * 512 + l * 4;
    float4 a = *(const float4*)pr;
    float4 b = *(const float4*)(pr + 256);
    uint4 w;
    w.x = f2bf(a.x) | (f2bf(a.y) << 16);
    w.y = f2bf(a.z) | (f2bf(a.w) << 16);
    w.z = f2bf(b.x) | (f2bf(b.y) << 16);
    w.w = f2bf(b.z) | (f2bf(b.w) << 16);
    ((uint4*)B16)[t] = w;
}

// ---------- fused persistent kernel: all 100 steps ----------
#define GATH(W) { float2 yy0 = y[(W) & 0xFFFFu]; a0 += yy0.x; a1 += yy0.y; \
                  float2 yy1 = y[(W) >> 16];     a0 += yy1.x; a1 += yy1.y; }

__global__ __launch_bounds__(1024) void k_fused(
    const uint16_t* __restrict__ B16, const float* __restrict__ az,
    const float* __restrict__ m, const float* __restrict__ se,
    const float* __restrict__ gse,
    const uint16_t* __restrict__ csr, const int* __restrict__ pad_ptr,
    const int* __restrict__ deg, const float* __restrict__ dinv,
    const float* __restrict__ rr,
    const float* __restrict__ W0, const float* __restrict__ b0,
    const float* __restrict__ Wh, const float* __restrict__ bh,
    float* __restrict__ vring, float* __restrict__ uring,
    float* __restrict__ out, float2* __restrict__ yring, int* __restrict__ bar) {
    __shared__ float2 y[NN + 1];         // gnn: y replica (+sentinel); mv: aliased float su[VD]
    float* su = (float*)y;
    const int bid = blockIdx.x;
    const int t = threadIdx.x;

    if ((bid & 31) == 0) {
        // ========= GNN role (bids 0,32,..,224: same XCD under round-robin) =========
        const int g = bid >> 5;                    // 0..7
        const bool act = t < 512;
        const int n = g * 512 + (t & 511);
        const float dv = dinv[n], rv = rr[n], dv2 = dv * dv;
        const int base = pad_ptr[n];
        const int nch = (deg[n] + 7) >> 3;
        const uint16_t* cp = csr + base;
        float dmy[4];
        for (int j = 0; j < 4; ++j) dmy[j] = dinv[j * 1024 + t];

        for (int step = 0; step < NSTEPS; ++step) {
            int* sb = bar + step * SSTR;
            const float* vin = vring + (size_t)step * VD;
            if (step > 0) {
                int* vd = sb - SSTR + 32;
                if (t < 64) {                      // wave 0: parallel 8-lane VDONE poll
                    int it = 0, ok = 0;
                    do {
                        int vv = (t < 8) ? __hip_atomic_load(vd + t * 16, __ATOMIC_RELAXED,
                                                             __HIP_MEMORY_SCOPE_AGENT) : 0;
                        for (int o = 4; o; o >>= 1) vv += __shfl_down(vv, o);
                        ok = (__shfl(vv, 0) >= MVW);
                        if (!ok) __builtin_amdgcn_s_sleep(2);
                    } while (!ok && ++it < (1 << 22));
                }
                __syncthreads();
                asm volatile("" ::: "memory");
            }
            // per-step layer-0 constants (redundant per thread; tiny, L2-hot)
            const float* gs = gse + 8 * step;
            float c0_0 = b0[0] + b0[2], c0_1 = b0[1] + b0[3];
            float c1_0 = 0.f, c1_1 = 0.f;
            for (int k = 0; k < 8; ++k) {
                float s = gs[k];
                c0_0 += s * W0[(2 + k) * 2 + 0];
                c0_1 += s * W0[(2 + k) * 2 + 1];
                c1_0 += s * W0[20 + (2 + k) * 2 + 0];
                c1_1 += s * W0[20 + (2 + k) * 2 + 1];
            }

            float x0 = 0.f, x1 = 0.f;
            if (act) { x0 = vin[n]; x1 = vin[n + NN]; }
            for (int j = 0; j < 4; ++j) {
                int mm = j * 1024 + t;
                y[mm] = make_float2(vin[mm] * dmy[j], vin[mm + NN] * dmy[j]);
            }
            if (t == 0) y[NN] = make_float2(0.f, 0.f);
            __syncthreads();

            for (int l = 0; l < 8; ++l) {
                float wa00, wa01, wa10, wa11, wb00, wb01, wb10, wb11, bb0, bb1, e0, e1;
                if (l == 0) {
                    wa00 = W0[0]; wa01 = W0[1]; wa10 = W0[2]; wa11 = W0[3];
                    wb00 = W0[20]; wb01 = W0[21]; wb10 = W0[22]; wb11 = W0[23];
                    bb0 = c0_0; bb1 = c0_1; e0 = c1_0; e1 = c1_1;
                } else {
                    const float* wl = Wh + (l - 1) * 8;
                    wa00 = wl[0]; wa01 = wl[1]; wa10 = wl[2]; wa11 = wl[3];
                    wb00 = wl[4]; wb01 = wl[5]; wb10 = wl[6]; wb11 = wl[7];
                    bb0 = bh[(l - 1) * 4 + 0] + bh[(l - 1) * 4 + 2];
                    bb1 = bh[(l - 1) * 4 + 1] + bh[(l - 1) * 4 + 3];
                    e0 = 0.f; e1 = 0.f;
                }

                if (act) {
                    float a0 = 0.f, a1 = 0.f;
                    for (int c = 0; c < nch; ++c) {
                        uint4 w = *(const uint4*)(cp + c * 8);
                        GATH(w.x) GATH(w.y) GATH(w.z) GATH(w.w)
                    }
                    float P0 = dv * a0 + dv2 * x0;
                    float P1 = dv * a1 + dv2 * x1;
                    float o0 = x0 * wa00 + x1 * wa10 + P0 * wb00 + P1 * wb10 + bb0 + rv * e0;
                    float o1 = x0 * wa01 + x1 * wa11 + P0 * wb01 + P1 * wb11 + bb1 + rv * e1;
                    x0 = fmaxf(o0, 0.f);
                    x1 = fmaxf(o1, 0.f);
                }

                if (l < 7) {
                    float2* yb = yring + (size_t)(step * 7 + l) * NN;   // fresh buffer
                    if (act) yb[n] = make_float2(x0 * dv, x1 * dv);
                    __syncthreads();        // LDS reads done; yb stores drained
                    if (t == 0) {
                        arrive(sb + l);     // release: pushes yb to coherence point
                        spin_ge<1>(sb + l, GWG);
                    }
                    __syncthreads();
                    asm volatile("" ::: "memory");
                    const float4* src = (const float4*)yb;   // same-XCD: L2-hot
                    float4* dst = (float4*)y;
                    for (int k = 0; k < 2; ++k) dst[k * 1024 + t] = src[k * 1024 + t];
                    __syncthreads();
                }
            }

            float* us = uring + (size_t)step * VD;
            if (act) { us[n] = x0; us[n + NN] = x1; }
            __syncthreads();                // u stores drained before publish
            if (t == 0) arrive(sb + 8);     // UREADY (release: pushes u)
        }
    } else {
        // =================== MV role (248 WGs, 33-34 rows, 16 waves) ===================
        const int j = bid - (bid >> 5) - 1;            // 0..247 over non-GNN bids
        const int row0 = j * 33 + (j < 8 ? j : 8);
        const int nrows = 33 + (j < 8 ? 1 : 0);
        const int wave = t >> 6, lane = t & 63;

        for (int step = 0; step < NSTEPS; ++step) {
            int* sb = bar + step * SSTR;
            int* flag = sb + 8;                        // UREADY
            if (t == 0) spin_ge<32>(flag, GWG);        // coarse backoff: 248 pollers
            __syncthreads();
            asm volatile("" ::: "memory");

            const float* us = uring + (size_t)step * VD;   // fresh buffer: cold-miss
            for (int i = 0; i < 2; ++i) {
                int c = i * 4096 + t * 4;
                *(float4*)&su[c] = *(const float4*)&us[c];
            }
            __syncthreads();

            float* vout = (step == NSTEPS - 1) ? out : vring + (size_t)(step + 1) * VD;
            const float* s = se + 8 * step;
            for (int rb = row0 + wave * 2; rb < row0 + nrows; rb += 32) {
                const int r0 = rb;
                const int r1 = rb + 1;
                const bool has1 = (r1 < row0 + nrows);
                const uint4* bp0 = (const uint4*)(B16 + (size_t)r0 * VD);
                const uint4* bp1 = (const uint4*)(B16 + (size_t)(has1 ? r1 : r0) * VD);
                float acc0 = 0.f, acc1 = 0.f;
                #pragma unroll
                for (int jj = 0; jj < 16; ++jj) {
                    uint4 w0 = bp0[jj * 64 + lane];    // straight loads: compiler pipelines
                    uint4 w1 = bp1[jj * 64 + lane];
                    int c = jj * 512 + lane * 4;
                    float4 ua = *(float4*)&su[c];      // 16B lane-stride: conflict-free
                    float4 ub = *(float4*)&su[c + 256];
                    acc0 += bfl(w0.x) * ua.x + bfh(w0.x) * ua.y + bfl(w0.y) * ua.z + bfh(w0.y) * ua.w
                          + bfl(w0.z) * ub.x + bfh(w0.z) * ub.y + bfl(w0.w) * ub.z + bfh(w0.w) * ub.w;
                    acc1 += bfl(w1.x) * ua.x + bfh(w1.x) * ua.y + bfl(w1.y) * ua.z + bfh(w1.y) * ua.w
                          + bfl(w1.z) * ub.x + bfh(w1.z) * ub.y + bfl(w1.w) * ub.z + bfh(w1.w) * ub.w;
                }
                for (int o = 32; o; o >>= 1) {
                    acc0 += __shfl_down(acc0, o);
                    acc1 += __shfl_down(acc1, o);
                }
                if (lane == 0) {
                    float cc0 = 0.f, cc1 = 0.f;
                    for (int k = 0; k < 8; ++k) {
                        cc0 += s[k] * m[r0 * 8 + k];
                        cc1 += s[k] * m[r1 * 8 + k];
                    }
                    vout[r0] = az[r0] + cc0 + acc0;
                    if (has1) vout[r1] = az[r1] + cc1 + acc1;
                }
            }
            __syncthreads();                // vout stores drained before publish
            if (t == 0) arrive(sb + 32 + (bid & 7) * 16);   // VDONE (release: pushes vout)
        }
    }
}

// ---------- launcher ----------
extern "C" void kernel_launch(void* const* d_in, const int* in_sizes, int n_in,
                              void* d_out, int out_size, void* d_ws, size_t ws_size,
                              hipStream_t stream) {
    const float* z   = (const float*)d_in[0];
    const int*   ei  = (const int*)d_in[1];
    const float* A_w = (const float*)d_in[2];
    const float* B_w = (const float*)d_in[3];
    const float* b_w = (const float*)d_in[4];
    const float* se  = (const float*)d_in[5];
    const float* gse = (const float*)d_in[6];
    const float* W0  = (const float*)d_in[7];
    const float* b0  = (const float*)d_in[8];
    const float* Wh  = (const float*)d_in[9];
    const float* bh  = (const float*)d_in[10];

    char* p = (char*)d_ws;
    auto carve = [&](size_t bytes) {
        void* r = (void*)p;
        p += (bytes + 255) & ~(size_t)255;
        return r;
    };
    uint16_t* B16    = (uint16_t*)carve((size_t)VD * VD * 2);
    float*    az     = (float*)carve(VD * 4);
    float*    m      = (float*)carve(VD * 8 * 4);
    float*    vring  = (float*)carve((size_t)(NSTEPS + 1) * VD * 4);  // rotated: no stale caches
    float*    uring  = (float*)carve((size_t)NSTEPS * VD * 4);
    int*      deg    = (int*)carve(NN * 4);
    int*      fill   = (int*)carve(NN * 4);
    int*      padp   = (int*)carve(NN * 4);
    float*    rr     = (float*)carve(NN * 4);
    float*    dinv   = (float*)carve((NN + 1) * 4);
    uint16_t* csr    = (uint16_t*)carve(CSR_CAP * 2);
    float2*   yring  = (float2*)carve((size_t)NSTEPS * 7 * NN * 8);   // rotated exchange bufs
    int*      bar    = (int*)carve((size_t)BARN * 4);

    k_zero<<<CSR_CAP / 2 / 256, 256, 0, stream>>>(deg, fill, vring, (uint32_t*)csr, bar);
    k_deg<<<NE / 256, 256, 0, stream>>>(ei, deg);
    k_scan<<<1, 1024, 0, stream>>>(deg, padp, dinv);
    k_fill<<<NE / 256, 256, 0, stream>>>(ei, padp, fill, csr);
    k_r<<<NN / 256, 256, 0, stream>>>(deg, padp, csr, dinv, rr);
    k_m<<<VD * 8 / 256, 256, 0, stream>>>(A_w, B_w, b_w, m);
    k_az<<<VD / 4, 256, 0, stream>>>(A_w, z, az);
    k_bconv<<<VD * 1024 / 256, 256, 0, stream>>>(B_w, B16);

    k_fused<<<NWG, TPB, 0, stream>>>(B16, az, m, se, gse, csr, padp, deg, dinv, rr,
                                     W0, b0, Wh, bh, vring, uring, (float*)d_out, yring, bar);
}

// Round 6
// 7307.409 us; speedup vs baseline: 1.3061x; 1.3061x over previous
//
#include <hip/hip_runtime.h>
#include <stdint.h>

#define NN 4096
#define VD 8192
#define NE 65536
#define NSTEPS 100
#define CSR_CAP 98304  // 65536 + worst-case per-node pad (<= 7*4096) rounded up

#define GWG 8          // GNN workgroups (bids 0,8,...,56)
#define NWG_STEP 520   // 8 GNN + 512 MV
#define SSTR 16        // barrier slot ints per step (EX:0..6, UREADY:8)
#define BARN (NSTEPS * SSTR)

// ---------- helpers ----------
__device__ __forceinline__ uint32_t f2bf(float f) {
    uint32_t x = __float_as_uint(f);
    return (x + 0x7FFFu + ((x >> 16) & 1u)) >> 16;
}
__device__ __forceinline__ float bfl(uint32_t w) { return __uint_as_float(w << 16); }
__device__ __forceinline__ float bfh(uint32_t w) { return __uint_as_float(w & 0xFFFF0000u); }

__device__ __forceinline__ void arrive(int* flag) {
    __hip_atomic_fetch_add(flag, 1, __ATOMIC_RELEASE, __HIP_MEMORY_SCOPE_AGENT);
}
template <int SLP>
__device__ __forceinline__ void spin_ge(int* flag, int target) {
    int it = 0;
    while (__hip_atomic_load(flag, __ATOMIC_RELAXED, __HIP_MEMORY_SCOPE_AGENT) < target) {
        __builtin_amdgcn_s_sleep(SLP);
        if (++it > (1 << 22)) break;  // safety bail: wrong answer beats hang
    }
}

// ---------- setup kernels ----------
__global__ void k_zero(int* deg, int* fill, float* v0, uint32_t* csrw, int* bar) {
    int t = blockIdx.x * 256 + threadIdx.x;           // grid covers 49152
    if (t < 4096) { deg[t] = 0; fill[t] = 0; }
    if (t < 8192) v0[t] = 0.f;                        // vring slot 0
    if (t < BARN) bar[t] = 0;                         // barrier slots (monotonic per slot)
    if (t < CSR_CAP / 2) csrw[t] = 0x10001000u;       // sentinel src = 4096
}

__global__ void k_deg(const int* ei, int* deg) {
    int e = blockIdx.x * 256 + threadIdx.x;
    if (e < NE) atomicAdd(&deg[ei[NE + e]], 1);
}

__global__ __launch_bounds__(1024) void k_scan(const int* deg, int* pad_ptr, float* dinv) {
    __shared__ int sh[1024];
    int t = threadIdx.x;
    int d[4], pl[4], tsum = 0;
    for (int j = 0; j < 4; ++j) {
        d[j] = deg[t * 4 + j];
        pl[j] = (d[j] + 7) & ~7;
        tsum += pl[j];
    }
    sh[t] = tsum;
    __syncthreads();
    for (int off = 1; off < 1024; off <<= 1) {
        int v = sh[t];
        if (t >= off) v += sh[t - off];
        __syncthreads();
        sh[t] = v;
        __syncthreads();
    }
    int base = sh[t] - tsum;  // exclusive prefix
    for (int j = 0; j < 4; ++j) {
        pad_ptr[t * 4 + j] = base;
        base += pl[j];
        dinv[t * 4 + j] = rsqrtf((float)(d[j] + 1));  // +1 self loop, always > 0
    }
    if (t == 0) dinv[4096] = 0.f;  // sentinel
}

__global__ void k_fill(const int* ei, const int* pad_ptr, int* fill, uint16_t* csr) {
    int e = blockIdx.x * 256 + threadIdx.x;
    if (e < NE) {
        int s = ei[e];
        int d = ei[NE + e];
        int pos = atomicAdd(&fill[d], 1);
        csr[pad_ptr[d] + pos] = (uint16_t)s;
    }
}

__global__ void k_r(const int* deg, const int* pad_ptr, const uint16_t* csr,
                    const float* dinv, float* rr) {
    int n = blockIdx.x * 256 + threadIdx.x;
    if (n >= NN) return;
    float dv = dinv[n];
    int base = pad_ptr[n];
    int nch = (deg[n] + 7) >> 3;
    float sum = 0.f;
    for (int c = 0; c < nch; ++c)
        for (int k = 0; k < 8; ++k) sum += dinv[csr[base + c * 8 + k]];  // sentinel adds 0
    rr[n] = dv * sum + dv * dv;
}

__global__ void k_m(const float* A, const float* B, const float* bw, float* m) {
    int t = blockIdx.x * 256 + threadIdx.x;  // 65536
    if (t >= VD * 8) return;
    int i = t >> 3, k = t & 7;
    m[t] = A[(size_t)i * 8200 + 8192 + k] + B[(size_t)i * 8200 + 8192 + k] + bw[i * 8 + k];
}

__global__ __launch_bounds__(256) void k_az(const float* A, const float* z, float* az) {
    int wave = threadIdx.x >> 6, lane = threadIdx.x & 63;
    int r = blockIdx.x * 4 + wave;
    const float* row = A + (size_t)r * 8200;
    float acc = 0.f;
    for (int j = 0; j < 32; ++j) {
        int c = j * 256 + lane * 4;
        float4 a = *(const float4*)(row + c);
        float4 zz = *(const float4*)(z + c);
        acc += a.x * zz.x + a.y * zz.y + a.z * zz.z + a.w * zz.w;
    }
    for (int o = 32; o; o >>= 1) acc += __shfl_down(acc, o);
    if (lane == 0) az[r] = acc;
}

// Permuted B16 layout: row r, uint4 index p = jj*64 + l holds bf16 of cols
// {jj*512+4l .. +3} (words x,y) and {jj*512+256+4l .. +3} (words z,w).
// This makes the mv-phase su reads two stride-4 float4s -> conflict-free LDS.
__global__ __launch_bounds__(256) void k_bconv(const float* B, uint16_t* B16) {
    int t = blockIdx.x * 256 + threadIdx.x;  // VD*1024 threads, one uint4 each
    int i = t >> 10;
    int p = t & 1023;
    int jj = p >> 6, l = p & 63;
    const float* pr = B + (size_t)i * 8200 + jj * 512 + l * 4;
    float4 a = *(const float4*)pr;
    float4 b = *(const float4*)(pr + 256);
    uint4 w;
    w.x = f2bf(a.x) | (f2bf(a.y) << 16);
    w.y = f2bf(a.z) | (f2bf(a.w) << 16);
    w.z = f2bf(b.x) | (f2bf(b.y) << 16);
    w.w = f2bf(b.z) | (f2bf(b.w) << 16);
    ((uint4*)B16)[t] = w;
}

// ---------- per-step kernel: GNN (8 WGs) + MV (512 WGs) with UREADY handoff ----------
#define GATH(W) { float2 yy0 = y[(W) & 0xFFFFu]; a0 += yy0.x; a1 += yy0.y; \
                  float2 yy1 = y[(W) >> 16];     a0 += yy1.x; a1 += yy1.y; }

__global__ __launch_bounds__(512) void k_step(
    const uint16_t* __restrict__ B16, const float* __restrict__ az,
    const float* __restrict__ m,
    const float* __restrict__ vin, float* __restrict__ vout,
    float* __restrict__ us, float2* __restrict__ ybase, int* __restrict__ sb,
    const uint16_t* __restrict__ csr, const int* __restrict__ pad_ptr,
    const int* __restrict__ deg, const float* __restrict__ dinv,
    const float* __restrict__ rr,
    const float* __restrict__ W0, const float* __restrict__ b0,
    const float* __restrict__ Wh, const float* __restrict__ bh,
    const float* __restrict__ s, const float* __restrict__ gs) {
    __shared__ float2 y[NN + 1];         // gnn: y replica (+sentinel); mv: aliased float su[VD]
    float* su = (float*)y;
    const int bid = blockIdx.x;
    const int t = threadIdx.x;
    int* ur = sb + 8;                    // UREADY flag

    if (bid < 64 && (bid & 7) == 0) {
        // ========= GNN role: 8 WGs (bids 0,8,..,56), 512 nodes each =========
        const int g = bid >> 3;
        const int n = g * 512 + t;
        const float dv = dinv[n], rv = rr[n], dv2 = dv * dv;
        const int base = pad_ptr[n];
        const int nch = (deg[n] + 7) >> 3;
        const uint16_t* cp = csr + base;
        float dmy[8];
        #pragma unroll
        for (int j = 0; j < 8; ++j) dmy[j] = dinv[j * 512 + t];

        // per-step layer-0 constants (redundant per thread; tiny, L2-hot)
        float c0_0 = b0[0] + b0[2], c0_1 = b0[1] + b0[3];
        float c1_0 = 0.f, c1_1 = 0.f;
        for (int k = 0; k < 8; ++k) {
            float sv = gs[k];
            c0_0 += sv * W0[(2 + k) * 2 + 0];
            c0_1 += sv * W0[(2 + k) * 2 + 1];
            c1_0 += sv * W0[20 + (2 + k) * 2 + 0];
            c1_1 += sv * W0[20 + (2 + k) * 2 + 1];
        }

        float x0 = vin[n], x1 = vin[n + NN];
        #pragma unroll
        for (int j = 0; j < 8; ++j) {
            int mm = j * 512 + t;
            y[mm] = make_float2(vin[mm] * dmy[j], vin[mm + NN] * dmy[j]);
        }
        if (t == 0) y[NN] = make_float2(0.f, 0.f);
        __syncthreads();

        for (int l = 0; l < 8; ++l) {
            float wa00, wa01, wa10, wa11, wb00, wb01, wb10, wb11, bb0, bb1, e0, e1;
            if (l == 0) {
                wa00 = W0[0]; wa01 = W0[1]; wa10 = W0[2]; wa11 = W0[3];
                wb00 = W0[20]; wb01 = W0[21]; wb10 = W0[22]; wb11 = W0[23];
                bb0 = c0_0; bb1 = c0_1; e0 = c1_0; e1 = c1_1;
            } else {
                const float* wl = Wh + (l - 1) * 8;
                wa00 = wl[0]; wa01 = wl[1]; wa10 = wl[2]; wa11 = wl[3];
                wb00 = wl[4]; wb01 = wl[5]; wb10 = wl[6]; wb11 = wl[7];
                bb0 = bh[(l - 1) * 4 + 0] + bh[(l - 1) * 4 + 2];
                bb1 = bh[(l - 1) * 4 + 1] + bh[(l - 1) * 4 + 3];
                e0 = 0.f; e1 = 0.f;
            }

            float a0 = 0.f, a1 = 0.f;
            for (int c = 0; c < nch; ++c) {
                uint4 w = *(const uint4*)(cp + c * 8);
                GATH(w.x) GATH(w.y) GATH(w.z) GATH(w.w)
            }
            float P0 = dv * a0 + dv2 * x0;
            float P1 = dv * a1 + dv2 * x1;
            float o0 = x0 * wa00 + x1 * wa10 + P0 * wb00 + P1 * wb10 + bb0 + rv * e0;
            float o1 = x0 * wa01 + x1 * wa11 + P0 * wb01 + P1 * wb11 + bb1 + rv * e1;
            x0 = fmaxf(o0, 0.f);
            x1 = fmaxf(o1, 0.f);

            if (l < 7) {
                float2* yb = ybase + (size_t)l * NN;   // fresh ring buffer per (step,layer)
                yb[n] = make_float2(x0 * dv, x1 * dv);
                __syncthreads();            // LDS reads done; yb stores drained
                if (t == 0) {
                    arrive(sb + l);         // release: pushes yb to coherence point
                    spin_ge<1>(sb + l, GWG);
                }
                __syncthreads();
                asm volatile("" ::: "memory");
                const float4* src = (const float4*)yb;   // fresh lines: L2-hit or L3-correct
                float4* dst = (float4*)y;
                #pragma unroll
                for (int k = 0; k < 4; ++k) dst[k * 512 + t] = src[k * 512 + t];
                __syncthreads();
            }
        }

        us[n] = x0;
        us[n + NN] = x1;
        __syncthreads();                    // u stores drained before publish
        if (t == 0) arrive(ur);             // UREADY (release: pushes u)
    } else {
        // ========= MV role: 512 WGs, 16 rows each (1 row per wave, 2 passes) =========
        const int j = (bid < 64) ? (bid - (bid >> 3) - 1) : (bid - 8);   // 0..511
        const int row0 = j * 16;
        const int wave = t >> 6, lane = t & 63;

        // warm first 4KB of this wave's first row into L2 while GNN runs (free overlap)
        {
            const uint4* bp = (const uint4*)(B16 + (size_t)(row0 + wave * 2) * VD);
            uint32_t wsum = 0;
            #pragma unroll
            for (int q = 0; q < 4; ++q) {
                uint4 ww = bp[q * 64 + lane];
                wsum += ww.x + ww.w;
            }
            asm volatile("" :: "v"(wsum));  // keep loads alive
        }

        if (t == 0) spin_ge<32>(ur, GWG);   // coarse backoff: 512 pollers
        __syncthreads();
        asm volatile("" ::: "memory");

        #pragma unroll
        for (int i = 0; i < 4; ++i) {       // stage u -> LDS (32 KB), fresh lines
            int c = i * 2048 + t * 4;
            *(float4*)&su[c] = *(const float4*)&us[c];
        }
        __syncthreads();

        for (int rp = 0; rp < 2; ++rp) {
            const int r = row0 + wave * 2 + rp;
            const uint4* bp = (const uint4*)(B16 + (size_t)r * VD);
            float acc = 0.f;
            #pragma unroll
            for (int jj = 0; jj < 16; ++jj) {
                uint4 w = bp[jj * 64 + lane];      // straight loads: compiler pipelines
                int c = jj * 512 + lane * 4;
                float4 ua = *(float4*)&su[c];      // 16B lane-stride: conflict-free
                float4 ub = *(float4*)&su[c + 256];
                acc += bfl(w.x) * ua.x + bfh(w.x) * ua.y + bfl(w.y) * ua.z + bfh(w.y) * ua.w
                     + bfl(w.z) * ub.x + bfh(w.z) * ub.y + bfl(w.w) * ub.z + bfh(w.w) * ub.w;
            }
            for (int o = 32; o; o >>= 1) acc += __shfl_down(acc, o);
            if (lane == 0) {
                float cc = 0.f;
                #pragma unroll
                for (int k = 0; k < 8; ++k) cc += s[k] * m[r * 8 + k];
                vout[r] = az[r] + cc + acc;
            }
        }
        // vout consumed by NEXT launch: launch boundary provides coherence
    }
}

// ---------- launcher ----------
extern "C" void kernel_launch(void* const* d_in, const int* in_sizes, int n_in,
                              void* d_out, int out_size, void* d_ws, size_t ws_size,
                              hipStream_t stream) {
    const float* z   = (const float*)d_in[0];
    const int*   ei  = (const int*)d_in[1];
    const float* A_w = (const float*)d_in[2];
    const float* B_w = (const float*)d_in[3];
    const float* b_w = (const float*)d_in[4];
    const float* se  = (const float*)d_in[5];
    const float* gse = (const float*)d_in[6];
    const float* W0  = (const float*)d_in[7];
    const float* b0  = (const float*)d_in[8];
    const float* Wh  = (const float*)d_in[9];
    const float* bh  = (const float*)d_in[10];

    char* p = (char*)d_ws;
    auto carve = [&](size_t bytes) {
        void* r = (void*)p;
        p += (bytes + 255) & ~(size_t)255;
        return r;
    };
    uint16_t* B16    = (uint16_t*)carve((size_t)VD * VD * 2);
    float*    az     = (float*)carve(VD * 4);
    float*    m      = (float*)carve(VD * 8 * 4);
    float*    vring  = (float*)carve((size_t)(NSTEPS + 1) * VD * 4);  // rotated: no stale caches
    float*    uring  = (float*)carve((size_t)NSTEPS * VD * 4);
    int*      deg    = (int*)carve(NN * 4);
    int*      fill   = (int*)carve(NN * 4);
    int*      padp   = (int*)carve(NN * 4);
    float*    rr     = (float*)carve(NN * 4);
    float*    dinv   = (float*)carve((NN + 1) * 4);
    uint16_t* csr    = (uint16_t*)carve(CSR_CAP * 2);
    float2*   yring  = (float2*)carve((size_t)NSTEPS * 7 * NN * 8);   // rotated exchange bufs
    int*      bar    = (int*)carve((size_t)BARN * 4);

    k_zero<<<CSR_CAP / 2 / 256, 256, 0, stream>>>(deg, fill, vring, (uint32_t*)csr, bar);
    k_deg<<<NE / 256, 256, 0, stream>>>(ei, deg);
    k_scan<<<1, 1024, 0, stream>>>(deg, padp, dinv);
    k_fill<<<NE / 256, 256, 0, stream>>>(ei, padp, fill, csr);
    k_r<<<NN / 256, 256, 0, stream>>>(deg, padp, csr, dinv, rr);
    k_m<<<VD * 8 / 256, 256, 0, stream>>>(A_w, B_w, b_w, m);
    k_az<<<VD / 4, 256, 0, stream>>>(A_w, z, az);
    k_bconv<<<VD * 1024 / 256, 256, 0, stream>>>(B_w, B16);

    for (int t = 0; t < NSTEPS; ++t) {
        float* vout = (t == NSTEPS - 1) ? (float*)d_out : vring + (size_t)(t + 1) * VD;
        k_step<<<NWG_STEP, 512, 0, stream>>>(B16, az, m,
                                             vring + (size_t)t * VD, vout,
                                             uring + (size_t)t * VD,
                                             yring + (size_t)t * 7 * NN,
                                             bar + t * SSTR,
                                             csr, padp, deg, dinv, rr,
                                             W0, b0, Wh, bh,
                                             se + 8 * t, gse + 8 * t);
    }
}

// Round 7
// 5283.283 us; speedup vs baseline: 1.8065x; 1.3831x over previous
//
#include <hip/hip_runtime.h>
#include <stdint.h>

#define NN 4096
#define VD 8192
#define NE 65536
#define NSTEPS 100
#define CSR_CAP 98304  // 65536 + worst-case per-node pad (<= 7*4096) rounded up

#define GWG 8          // GNN workgroups (active bids 0,8,...,56 of a 64-block launch)
#define SSTR 8         // barrier slot ints per step (EX flags 0..6)
#define BARN (NSTEPS * SSTR)

// ---------- helpers ----------
__device__ __forceinline__ uint32_t f2bf(float f) {
    uint32_t x = __float_as_uint(f);
    return (x + 0x7FFFu + ((x >> 16) & 1u)) >> 16;
}
__device__ __forceinline__ float bfl(uint32_t w) { return __uint_as_float(w << 16); }
__device__ __forceinline__ float bfh(uint32_t w) { return __uint_as_float(w & 0xFFFF0000u); }

__device__ __forceinline__ void arrive(int* flag) {
    __hip_atomic_fetch_add(flag, 1, __ATOMIC_RELEASE, __HIP_MEMORY_SCOPE_AGENT);
}
template <int SLP>
__device__ __forceinline__ void spin_ge(int* flag, int target) {
    int it = 0;
    while (__hip_atomic_load(flag, __ATOMIC_RELAXED, __HIP_MEMORY_SCOPE_AGENT) < target) {
        __builtin_amdgcn_s_sleep(SLP);
        if (++it > (1 << 22)) break;  // safety bail: wrong answer beats hang
    }
}

// ---------- setup kernels ----------
__global__ void k_zero(int* deg, int* fill, float* v0, uint32_t* csrw, int* bar) {
    int t = blockIdx.x * 256 + threadIdx.x;           // grid covers 49152
    if (t < 4096) { deg[t] = 0; fill[t] = 0; }
    if (t < 8192) v0[t] = 0.f;                        // vring slot 0
    if (t < BARN) bar[t] = 0;                         // barrier slots (monotonic per slot)
    if (t < CSR_CAP / 2) csrw[t] = 0x10001000u;       // sentinel src = 4096
}

__global__ void k_deg(const int* ei, int* deg) {
    int e = blockIdx.x * 256 + threadIdx.x;
    if (e < NE) atomicAdd(&deg[ei[NE + e]], 1);
}

__global__ __launch_bounds__(1024) void k_scan(const int* deg, int* pad_ptr, float* dinv) {
    __shared__ int sh[1024];
    int t = threadIdx.x;
    int d[4], pl[4], tsum = 0;
    for (int j = 0; j < 4; ++j) {
        d[j] = deg[t * 4 + j];
        pl[j] = (d[j] + 7) & ~7;
        tsum += pl[j];
    }
    sh[t] = tsum;
    __syncthreads();
    for (int off = 1; off < 1024; off <<= 1) {
        int v = sh[t];
        if (t >= off) v += sh[t - off];
        __syncthreads();
        sh[t] = v;
        __syncthreads();
    }
    int base = sh[t] - tsum;  // exclusive prefix
    for (int j = 0; j < 4; ++j) {
        pad_ptr[t * 4 + j] = base;
        base += pl[j];
        dinv[t * 4 + j] = rsqrtf((float)(d[j] + 1));  // +1 self loop, always > 0
    }
    if (t == 0) dinv[4096] = 0.f;  // sentinel
}

__global__ void k_fill(const int* ei, const int* pad_ptr, int* fill, uint16_t* csr) {
    int e = blockIdx.x * 256 + threadIdx.x;
    if (e < NE) {
        int s = ei[e];
        int d = ei[NE + e];
        int pos = atomicAdd(&fill[d], 1);
        csr[pad_ptr[d] + pos] = (uint16_t)s;
    }
}

__global__ void k_r(const int* deg, const int* pad_ptr, const uint16_t* csr,
                    const float* dinv, float* rr) {
    int n = blockIdx.x * 256 + threadIdx.x;
    if (n >= NN) return;
    float dv = dinv[n];
    int base = pad_ptr[n];
    int nch = (deg[n] + 7) >> 3;
    float sum = 0.f;
    for (int c = 0; c < nch; ++c)
        for (int k = 0; k < 8; ++k) sum += dinv[csr[base + c * 8 + k]];  // sentinel adds 0
    rr[n] = dv * sum + dv * dv;
}

__global__ void k_m(const float* A, const float* B, const float* bw, float* m) {
    int t = blockIdx.x * 256 + threadIdx.x;  // 65536
    if (t >= VD * 8) return;
    int i = t >> 3, k = t & 7;
    m[t] = A[(size_t)i * 8200 + 8192 + k] + B[(size_t)i * 8200 + 8192 + k] + bw[i * 8 + k];
}

__global__ __launch_bounds__(256) void k_az(const float* A, const float* z, float* az) {
    int wave = threadIdx.x >> 6, lane = threadIdx.x & 63;
    int r = blockIdx.x * 4 + wave;
    const float* row = A + (size_t)r * 8200;
    float acc = 0.f;
    for (int j = 0; j < 32; ++j) {
        int c = j * 256 + lane * 4;
        float4 a = *(const float4*)(row + c);
        float4 zz = *(const float4*)(z + c);
        acc += a.x * zz.x + a.y * zz.y + a.z * zz.z + a.w * zz.w;
    }
    for (int o = 32; o; o >>= 1) acc += __shfl_down(acc, o);
    if (lane == 0) az[r] = acc;
}

// Permuted B16 layout: row r, uint4 index p = jj*64 + l holds bf16 of cols
// {jj*512+4l .. +3} (words x,y) and {jj*512+256+4l .. +3} (words z,w).
// This makes the mv-phase su reads contiguous 16B/lane -> conflict-free LDS.
__global__ __launch_bounds__(256) void k_bconv(const float* B, uint16_t* B16) {
    int t = blockIdx.x * 256 + threadIdx.x;  // VD*1024 threads, one uint4 each
    int i = t >> 10;
    int p = t & 1023;
    int jj = p >> 6, l = p & 63;
    const float* pr = B + (size_t)i * 8200 + jj * 512 + l * 4;
    float4 a = *(const float4*)pr;
    float4 b = *(const float4*)(pr + 256);
    uint4 w;
    w.x = f2bf(a.x) | (f2bf(a.y) << 16);
    w.y = f2bf(a.z) | (f2bf(a.w) << 16);
    w.z = f2bf(b.x) | (f2bf(b.y) << 16);
    w.w = f2bf(b.z) | (f2bf(b.w) << 16);
    ((uint4*)B16)[t] = w;
}

// ---------- per-step GNN: 8 active WGs (same XCD), LDS-replicated y, ring exchange ----------
#define GATH(W) { float2 yy0 = y[(W) & 0xFFFFu]; a0 += yy0.x; a1 += yy0.y; \
                  float2 yy1 = y[(W) >> 16];     a0 += yy1.x; a1 += yy1.y; }

__global__ __launch_bounds__(512) void k_gnn(
    const float* __restrict__ vin, float* __restrict__ us,
    float2* __restrict__ ybase, int* __restrict__ sb,
    const uint16_t* __restrict__ csr, const int* __restrict__ pad_ptr,
    const int* __restrict__ deg, const float* __restrict__ dinv,
    const float* __restrict__ rr,
    const float* __restrict__ W0, const float* __restrict__ b0,
    const float* __restrict__ Wh, const float* __restrict__ bh,
    const float* __restrict__ gs) {
    const int bid = blockIdx.x;
    if (bid & 7) return;                 // active: 0,8,..,56 -> one XCD under bid%8 round-robin
    __shared__ float2 y[NN + 1];         // y[n] = x[n]*dinv[n]; y[4096] = 0 sentinel
    const int g = bid >> 3;              // 0..7
    const int t = threadIdx.x;           // 0..511
    const int n = g * 512 + t;

    const float dv = dinv[n], rv = rr[n], dv2 = dv * dv;
    const int base = pad_ptr[n];
    const int nch = (deg[n] + 7) >> 3;
    const uint16_t* cp = csr + base;
    float dmy[8];
    #pragma unroll
    for (int j = 0; j < 8; ++j) dmy[j] = dinv[j * 512 + t];

    // per-step layer-0 constants (redundant per thread; tiny, L2-hot)
    float c0_0 = b0[0] + b0[2], c0_1 = b0[1] + b0[3];
    float c1_0 = 0.f, c1_1 = 0.f;
    for (int k = 0; k < 8; ++k) {
        float sv = gs[k];
        c0_0 += sv * W0[(2 + k) * 2 + 0];
        c0_1 += sv * W0[(2 + k) * 2 + 1];
        c1_0 += sv * W0[20 + (2 + k) * 2 + 0];
        c1_1 += sv * W0[20 + (2 + k) * 2 + 1];
    }

    float x0 = vin[n], x1 = vin[n + NN];
    #pragma unroll
    for (int j = 0; j < 8; ++j) {
        int mm = j * 512 + t;
        y[mm] = make_float2(vin[mm] * dmy[j], vin[mm + NN] * dmy[j]);
    }
    if (t == 0) y[NN] = make_float2(0.f, 0.f);
    __syncthreads();

    for (int l = 0; l < 8; ++l) {
        float wa00, wa01, wa10, wa11, wb00, wb01, wb10, wb11, bb0, bb1, e0, e1;
        if (l == 0) {
            wa00 = W0[0]; wa01 = W0[1]; wa10 = W0[2]; wa11 = W0[3];
            wb00 = W0[20]; wb01 = W0[21]; wb10 = W0[22]; wb11 = W0[23];
            bb0 = c0_0; bb1 = c0_1; e0 = c1_0; e1 = c1_1;
        } else {
            const float* wl = Wh + (l - 1) * 8;
            wa00 = wl[0]; wa01 = wl[1]; wa10 = wl[2]; wa11 = wl[3];
            wb00 = wl[4]; wb01 = wl[5]; wb10 = wl[6]; wb11 = wl[7];
            bb0 = bh[(l - 1) * 4 + 0] + bh[(l - 1) * 4 + 2];
            bb1 = bh[(l - 1) * 4 + 1] + bh[(l - 1) * 4 + 3];
            e0 = 0.f; e1 = 0.f;
        }

        float a0 = 0.f, a1 = 0.f;
        for (int c = 0; c < nch; ++c) {
            uint4 w = *(const uint4*)(cp + c * 8);
            GATH(w.x) GATH(w.y) GATH(w.z) GATH(w.w)
        }
        float P0 = dv * a0 + dv2 * x0;
        float P1 = dv * a1 + dv2 * x1;
        float o0 = x0 * wa00 + x1 * wa10 + P0 * wb00 + P1 * wb10 + bb0 + rv * e0;
        float o1 = x0 * wa01 + x1 * wa11 + P0 * wb01 + P1 * wb11 + bb1 + rv * e1;
        x0 = fmaxf(o0, 0.f);
        x1 = fmaxf(o1, 0.f);

        if (l < 7) {
            float2* yb = ybase + (size_t)l * NN;   // fresh ring buffer per (step,layer)
            yb[n] = make_float2(x0 * dv, x1 * dv);
            __syncthreads();            // LDS reads done; yb stores drained
            if (t == 0) {
                arrive(sb + l);         // release: pushes yb to coherence point
                spin_ge<1>(sb + l, GWG);
            }
            __syncthreads();
            asm volatile("" ::: "memory");
            const float4* src = (const float4*)yb;   // same-XCD: L2-hot
            float4* dst = (float4*)y;
            #pragma unroll
            for (int k = 0; k < 4; ++k) dst[k * 512 + t] = src[k * 512 + t];
            __syncthreads();
        }
    }

    us[n] = x0;
    us[n + NN] = x1;
    // launch boundary provides coherence to k_mv
}

// ---------- per-step matvec: vout = az + m@s + B16 @ u (permuted, conflict-free) ----------
__global__ __launch_bounds__(256) void k_mv(const uint16_t* __restrict__ B16,
                                            const float* __restrict__ u,
                                            const float* __restrict__ az,
                                            const float* __restrict__ m,
                                            const float* __restrict__ s,
                                            float* __restrict__ vout) {
    __shared__ float su[VD];
    int t = threadIdx.x;
    #pragma unroll
    for (int i = 0; i < 8; ++i) {
        int c = i * 1024 + t * 4;
        *(float4*)&su[c] = *(const float4*)&u[c];
    }
    __syncthreads();
    int wave = t >> 6, lane = t & 63;
    int r = blockIdx.x * 4 + wave;
    const uint4* bp = (const uint4*)(B16 + (size_t)r * VD);
    float acc = 0.f;
    #pragma unroll
    for (int jj = 0; jj < 16; ++jj) {
        uint4 w = bp[jj * 64 + lane];          // straight loads: compiler pipelines
        int c = jj * 512 + lane * 4;
        float4 ua = *(float4*)&su[c];          // contiguous 16B/lane: conflict-free
        float4 ub = *(float4*)&su[c + 256];
        acc += bfl(w.x) * ua.x + bfh(w.x) * ua.y + bfl(w.y) * ua.z + bfh(w.y) * ua.w
             + bfl(w.z) * ub.x + bfh(w.z) * ub.y + bfl(w.w) * ub.z + bfh(w.w) * ub.w;
    }
    for (int o = 32; o; o >>= 1) acc += __shfl_down(acc, o);
    if (lane == 0) {
        float cc = 0.f;
        #pragma unroll
        for (int k = 0; k < 8; ++k) cc += s[k] * m[r * 8 + k];
        vout[r] = az[r] + cc + acc;
    }
}

// ---------- launcher ----------
extern "C" void kernel_launch(void* const* d_in, const int* in_sizes, int n_in,
                              void* d_out, int out_size, void* d_ws, size_t ws_size,
                              hipStream_t stream) {
    const float* z   = (const float*)d_in[0];
    const int*   ei  = (const int*)d_in[1];
    const float* A_w = (const float*)d_in[2];
    const float* B_w = (const float*)d_in[3];
    const float* b_w = (const float*)d_in[4];
    const float* se  = (const float*)d_in[5];
    const float* gse = (const float*)d_in[6];
    const float* W0  = (const float*)d_in[7];
    const float* b0  = (const float*)d_in[8];
    const float* Wh  = (const float*)d_in[9];
    const float* bh  = (const float*)d_in[10];

    char* p = (char*)d_ws;
    auto carve = [&](size_t bytes) {
        void* r = (void*)p;
        p += (bytes + 255) & ~(size_t)255;
        return r;
    };
    uint16_t* B16    = (uint16_t*)carve((size_t)VD * VD * 2);
    float*    az     = (float*)carve(VD * 4);
    float*    m      = (float*)carve(VD * 8 * 4);
    float*    vring  = (float*)carve((size_t)(NSTEPS + 1) * VD * 4);  // rotated v buffers
    float*    u      = (float*)carve(VD * 4);
    int*      deg    = (int*)carve(NN * 4);
    int*      fill   = (int*)carve(NN * 4);
    int*      padp   = (int*)carve(NN * 4);
    float*    rr     = (float*)carve(NN * 4);
    float*    dinv   = (float*)carve((NN + 1) * 4);
    uint16_t* csr    = (uint16_t*)carve(CSR_CAP * 2);
    float2*   yring  = (float2*)carve((size_t)NSTEPS * 7 * NN * 8);   // rotated exchange bufs
    int*      bar    = (int*)carve((size_t)BARN * 4);

    k_zero<<<CSR_CAP / 2 / 256, 256, 0, stream>>>(deg, fill, vring, (uint32_t*)csr, bar);
    k_deg<<<NE / 256, 256, 0, stream>>>(ei, deg);
    k_scan<<<1, 1024, 0, stream>>>(deg, padp, dinv);
    k_fill<<<NE / 256, 256, 0, stream>>>(ei, padp, fill, csr);
    k_r<<<NN / 256, 256, 0, stream>>>(deg, padp, csr, dinv, rr);
    k_m<<<VD * 8 / 256, 256, 0, stream>>>(A_w, B_w, b_w, m);
    k_az<<<VD / 4, 256, 0, stream>>>(A_w, z, az);
    k_bconv<<<VD * 1024 / 256, 256, 0, stream>>>(B_w, B16);

    for (int t = 0; t < NSTEPS; ++t) {
        float* vout = (t == NSTEPS - 1) ? (float*)d_out : vring + (size_t)(t + 1) * VD;
        k_gnn<<<64, 512, 0, stream>>>(vring + (size_t)t * VD, u,
                                      yring + (size_t)t * 7 * NN, bar + t * SSTR,
                                      csr, padp, deg, dinv, rr,
                                      W0, b0, Wh, bh, gse + 8 * t);
        k_mv<<<VD / 4, 256, 0, stream>>>(B16, u, az, m, se + 8 * t, vout);
    }
}